// Round 1
// baseline (994.581 us; speedup 1.0000x reference)
//
#include <hip/hip_runtime.h>
#include <math.h>

namespace {

constexpr int Bn  = 8;
constexpr int Nn  = 500;
constexpr int Qn  = 25;
constexpr int ENC = 512;
constexpr int DIN = 300;
constexpr int NCn = 70;
constexpr int NETn = 3;

__device__ __forceinline__ float sigmoidf_(float x) { return 1.0f / (1.0f + expf(-x)); }

__device__ __forceinline__ float rowmask_of(int row, const int* __restrict__ lens) {
    int b = row / Nn;
    int i = row - b * Nn;
    return (i < lens[b]) ? 1.0f : 0.0f;
}

// ---------------------------------------------------------------------------
// A_sum[b,i,j] = sum_e adj[b,e,i,j]
__global__ __launch_bounds__(256) void sum_adj_k(const float* __restrict__ adj,
                                                 float* __restrict__ Asum) {
    size_t i = (size_t)blockIdx.x * 256 + threadIdx.x;
    constexpr size_t NN = (size_t)Nn * Nn;
    if (i >= (size_t)Bn * NN) return;
    size_t b = i / NN, r = i - b * NN;
    const float* base = adj + (b * NETn) * NN + r;
    Asum[i] = base[0] + base[NN] + base[2 * NN];
}

// ---------------------------------------------------------------------------
// Generic tiled SGEMM: C = epi(A @ W + bias).  64x64 tile, BK=16, 4x4/thread.
// EPI 0: tv = tanh(v); C = tv; C2 = tv*rowmask   (nodes_compress + last_hop)
// EPI 1: C = v                                    (query_compress)
// EPI 2: C = v * rowmask                          (hm)
template <int EPI>
__global__ __launch_bounds__(256) void sgemm_k(const float* __restrict__ A,
                                               const float* __restrict__ W,
                                               const float* __restrict__ bias,
                                               float* __restrict__ C,
                                               float* __restrict__ C2,
                                               int M, int N, int K,
                                               const int* __restrict__ lens) {
    __shared__ float As[16][64 + 4];
    __shared__ float Ws[16][64];
    int t = threadIdx.x;
    int m0 = blockIdx.x * 64;
    int n0 = blockIdx.y * 64;
    int tm = t >> 4, tn = t & 15;
    int la_r = t >> 2;
    int la_k = (t & 3) * 4;
    int lw_r = t >> 4;
    int lw_n = (t & 15) * 4;

    float acc[4][4] = {};
    int ktiles = (K + 15) >> 4;
    for (int kt = 0; kt < ktiles; ++kt) {
        int k0 = kt << 4;
        {   // A tile (stored transposed As[k][m])
            int row = m0 + la_r;
            int kg  = k0 + la_k;
            if (row < M && kg + 4 <= K) {
                float4 v = *(const float4*)(A + (size_t)row * K + kg);
                As[la_k + 0][la_r] = v.x; As[la_k + 1][la_r] = v.y;
                As[la_k + 2][la_r] = v.z; As[la_k + 3][la_r] = v.w;
            } else {
                for (int u = 0; u < 4; ++u) {
                    int kk = kg + u;
                    As[la_k + u][la_r] = (row < M && kk < K) ? A[(size_t)row * K + kk] : 0.0f;
                }
            }
        }
        {   // W tile
            int kr = k0 + lw_r;
            float4 v = make_float4(0.f, 0.f, 0.f, 0.f);
            if (kr < K) v = *(const float4*)(W + (size_t)kr * N + n0 + lw_n);
            *(float4*)&Ws[lw_r][lw_n] = v;
        }
        __syncthreads();
#pragma unroll
        for (int kk = 0; kk < 16; ++kk) {
            float4 av = *(const float4*)&As[kk][tm * 4];
            float4 bv = *(const float4*)&Ws[kk][tn * 4];
            float a_[4] = {av.x, av.y, av.z, av.w};
            float b_[4] = {bv.x, bv.y, bv.z, bv.w};
#pragma unroll
            for (int i = 0; i < 4; ++i)
#pragma unroll
                for (int j = 0; j < 4; ++j) acc[i][j] = fmaf(a_[i], b_[j], acc[i][j]);
        }
        __syncthreads();
    }
    for (int i = 0; i < 4; ++i) {
        int row = m0 + tm * 4 + i;
        if (row >= M) break;
        float rm = (EPI != 1) ? rowmask_of(row, lens) : 1.0f;
        for (int j = 0; j < 4; ++j) {
            int n = n0 + tn * 4 + j;
            float v = acc[i][j] + bias[n];
            if (EPI == 0) {
                float tv = tanhf(v);
                C[(size_t)row * N + n]  = tv;
                C2[(size_t)row * N + n] = tv * rm;
            } else if (EPI == 1) {
                C[(size_t)row * N + n] = v;
            } else {
                C[(size_t)row * N + n] = v * rm;
            }
        }
    }
}

// ---------------------------------------------------------------------------
// update[b] = Asum[b] (500x500) @ hm[b] (500x512) + hm[b]
__global__ __launch_bounds__(256) void bgemm_update_k(const float* __restrict__ Asum,
                                                      const float* __restrict__ hm,
                                                      float* __restrict__ upd) {
    __shared__ float As[16][64 + 4];
    __shared__ float Ws[16][64];
    int b = blockIdx.z;
    const float* A = Asum + (size_t)b * Nn * Nn;
    const float* W = hm + (size_t)b * Nn * ENC;
    int t = threadIdx.x;
    int m0 = blockIdx.x * 64;
    int n0 = blockIdx.y * 64;
    int tm = t >> 4, tn = t & 15;
    int la_r = t >> 2;
    int la_k = (t & 3) * 4;
    int lw_r = t >> 4;
    int lw_n = (t & 15) * 4;
    constexpr int M = Nn, N = ENC, K = Nn;

    float acc[4][4] = {};
    int ktiles = (K + 15) >> 4;
    for (int kt = 0; kt < ktiles; ++kt) {
        int k0 = kt << 4;
        {
            int row = m0 + la_r;
            int kg  = k0 + la_k;
            if (row < M && kg + 4 <= K) {
                float4 v = *(const float4*)(A + (size_t)row * K + kg);
                As[la_k + 0][la_r] = v.x; As[la_k + 1][la_r] = v.y;
                As[la_k + 2][la_r] = v.z; As[la_k + 3][la_r] = v.w;
            } else {
                for (int u = 0; u < 4; ++u) {
                    int kk = kg + u;
                    As[la_k + u][la_r] = (row < M && kk < K) ? A[(size_t)row * K + kk] : 0.0f;
                }
            }
        }
        {
            int kr = k0 + lw_r;
            float4 v = make_float4(0.f, 0.f, 0.f, 0.f);
            if (kr < K) v = *(const float4*)(W + (size_t)kr * N + n0 + lw_n);
            *(float4*)&Ws[lw_r][lw_n] = v;
        }
        __syncthreads();
#pragma unroll
        for (int kk = 0; kk < 16; ++kk) {
            float4 av = *(const float4*)&As[kk][tm * 4];
            float4 bv = *(const float4*)&Ws[kk][tn * 4];
            float a_[4] = {av.x, av.y, av.z, av.w};
            float b_[4] = {bv.x, bv.y, bv.z, bv.w};
#pragma unroll
            for (int i = 0; i < 4; ++i)
#pragma unroll
                for (int j = 0; j < 4; ++j) acc[i][j] = fmaf(a_[i], b_[j], acc[i][j]);
        }
        __syncthreads();
    }
    for (int i = 0; i < 4; ++i) {
        int row = m0 + tm * 4 + i;
        if (row >= M) break;
        for (int j = 0; j < 4; ++j) {
            int n = n0 + tn * 4 + j;
            float v = acc[i][j] + W[(size_t)row * N + n];  // + hm[b,row,n]
            upd[((size_t)b * Nn + row) * ENC + n] = v;
        }
    }
}

// ---------------------------------------------------------------------------
// att = sigmoid([upd | lh] @ Wc + bc) * rowmask ;  lh_out = att*tanh(upd) + (1-att)*lh
__global__ __launch_bounds__(256) void gemm_att_k(const float* __restrict__ upd,
                                                  const float* __restrict__ lh,
                                                  const float* __restrict__ Wc,
                                                  const float* __restrict__ bc,
                                                  float* __restrict__ lh_out,
                                                  const int* __restrict__ lens) {
    __shared__ float As[16][64 + 4];
    __shared__ float Ws[16][64];
    int t = threadIdx.x;
    int m0 = blockIdx.x * 64;
    int n0 = blockIdx.y * 64;
    int tm = t >> 4, tn = t & 15;
    int la_r = t >> 2;
    int la_k = (t & 3) * 4;
    int lw_r = t >> 4;
    int lw_n = (t & 15) * 4;
    constexpr int M = Bn * Nn, N = ENC, K = 2 * ENC;

    float acc[4][4] = {};
    for (int kt = 0; kt < K / 16; ++kt) {
        int k0 = kt << 4;
        {
            int row = m0 + la_r;
            int kg  = k0 + la_k;
            float4 v = make_float4(0.f, 0.f, 0.f, 0.f);
            if (row < M) {
                const float* src = (kg < ENC) ? (upd + (size_t)row * ENC + kg)
                                              : (lh + (size_t)row * ENC + (kg - ENC));
                v = *(const float4*)src;
            }
            As[la_k + 0][la_r] = v.x; As[la_k + 1][la_r] = v.y;
            As[la_k + 2][la_r] = v.z; As[la_k + 3][la_r] = v.w;
        }
        {
            int kr = k0 + lw_r;
            *(float4*)&Ws[lw_r][lw_n] = *(const float4*)(Wc + (size_t)kr * N + n0 + lw_n);
        }
        __syncthreads();
#pragma unroll
        for (int kk = 0; kk < 16; ++kk) {
            float4 av = *(const float4*)&As[kk][tm * 4];
            float4 bv = *(const float4*)&Ws[kk][tn * 4];
            float a_[4] = {av.x, av.y, av.z, av.w};
            float b_[4] = {bv.x, bv.y, bv.z, bv.w};
#pragma unroll
            for (int i = 0; i < 4; ++i)
#pragma unroll
                for (int j = 0; j < 4; ++j) acc[i][j] = fmaf(a_[i], b_[j], acc[i][j]);
        }
        __syncthreads();
    }
    for (int i = 0; i < 4; ++i) {
        int row = m0 + tm * 4 + i;
        if (row >= M) break;
        float rm = rowmask_of(row, lens);
        for (int j = 0; j < 4; ++j) {
            int n = n0 + tn * 4 + j;
            float a = sigmoidf_(acc[i][j] + bc[n]) * rm;
            float u = upd[(size_t)row * ENC + n];
            float l = lh[(size_t)row * ENC + n];
            lh_out[(size_t)row * ENC + n] = a * tanhf(u) + (1.0f - a) * l;
        }
    }
}

// ---------------------------------------------------------------------------
// Fused: sim -> softmax over q -> nodes2query; also rowmax (max over q) per node.
// grid (B, 16), block 256 (4 waves, one row per wave at a time).
__global__ __launch_bounds__(256) void sim_fused_k(const float* __restrict__ lh,
                                                   const float* __restrict__ qc,
                                                   const float* __restrict__ wa,
                                                   float* __restrict__ n2q,
                                                   float* __restrict__ rowmax) {
    __shared__ float qcs[Qn * ENC];  // 51.2 KB
    __shared__ float qdot[Qn];
    int b = blockIdx.x;
    int t = threadIdx.x;
    const float* qcb = qc + (size_t)b * Qn * ENC;
    for (int i = t * 4; i < Qn * ENC; i += 256 * 4) *(float4*)&qcs[i] = *(const float4*)&qcb[i];
    __syncthreads();
    int wave = t >> 6, lane = t & 63;
    for (int q = wave; q < Qn; q += 4) {
        float p = 0.f;
        for (int d = lane; d < ENC; d += 64) p += qcs[q * ENC + d] * wa[ENC + d];
        for (int off = 32; off; off >>= 1) p += __shfl_xor(p, off, 64);
        if (lane == 0) qdot[q] = p;
    }
    __syncthreads();

    int nstart = blockIdx.y * 32;
    int nend = min(Nn, nstart + 32);
    for (int n = nstart + wave; n < nend; n += 4) {
        const float* lrow = lh + ((size_t)b * Nn + n) * ENC;
        float lvs[8];
        float ndot = 0.f;
#pragma unroll
        for (int it = 0; it < 8; ++it) {
            int d = lane + it * 64;
            float lv = lrow[d];
            ndot += lv * wa[d];
            lvs[it] = lv * wa[2 * ENC + d];
        }
        for (int off = 32; off; off >>= 1) ndot += __shfl_xor(ndot, off, 64);
        float s[Qn];
        for (int q = 0; q < Qn; ++q) {
            float p = 0.f;
#pragma unroll
            for (int it = 0; it < 8; ++it) p += lvs[it] * qcs[q * ENC + lane + it * 64];
            for (int off = 32; off; off >>= 1) p += __shfl_xor(p, off, 64);
            s[q] = p + ndot + qdot[q];
        }
        float m = s[0];
        for (int q = 1; q < Qn; ++q) m = fmaxf(m, s[q]);
        float sum = 0.f;
        for (int q = 0; q < Qn; ++q) { s[q] = expf(s[q] - m); sum += s[q]; }
        float inv = 1.0f / sum;
#pragma unroll
        for (int it = 0; it < 8; ++it) {
            int d = lane + it * 64;
            float o = 0.f;
            for (int q = 0; q < Qn; ++q) o += s[q] * qcs[q * ENC + d];
            n2q[((size_t)b * Nn + n) * ENC + d] = o * inv;
        }
        if (lane == 0) rowmax[b * Nn + n] = m;
    }
}

// ---------------------------------------------------------------------------
// bvec = softmax over n of rowmax.  grid B, block 512.
__global__ __launch_bounds__(512) void bvec_k(const float* __restrict__ rowmax,
                                              float* __restrict__ bvec) {
    __shared__ float red[8];
    int b = blockIdx.x, t = threadIdx.x;
    float v = (t < Nn) ? rowmax[b * Nn + t] : -INFINITY;
    float m = v;
    for (int off = 32; off; off >>= 1) m = fmaxf(m, __shfl_xor(m, off, 64));
    if ((t & 63) == 0) red[t >> 6] = m;
    __syncthreads();
    float bm = red[0];
    for (int i = 1; i < 8; ++i) bm = fmaxf(bm, red[i]);
    float e = (t < Nn) ? expf(v - bm) : 0.0f;
    float ssum = e;
    for (int off = 32; off; off >>= 1) ssum += __shfl_xor(ssum, off, 64);
    __syncthreads();
    if ((t & 63) == 0) red[t >> 6] = ssum;
    __syncthreads();
    float tot = 0.f;
    for (int i = 0; i < 8; ++i) tot += red[i];
    if (t < Nn) bvec[b * Nn + t] = e / tot;
}

// ---------------------------------------------------------------------------
// q2n[b,d] = sum_n bvec[b,n] * nc[b,n,d].  grid (B, 2), block 256.
__global__ __launch_bounds__(256) void q2n_k(const float* __restrict__ bvec,
                                             const float* __restrict__ nc,
                                             float* __restrict__ q2n) {
    int b = blockIdx.x;
    int d = blockIdx.y * 256 + threadIdx.x;
    const float* ncb = nc + (size_t)b * Nn * ENC;
    float acc = 0.f;
    for (int n = 0; n < Nn; ++n) acc = fmaf(bvec[b * Nn + n], ncb[(size_t)n * ENC + d], acc);
    q2n[b * ENC + d] = acc;
}

// ---------------------------------------------------------------------------
// raw[m] = tanh(g[m] @ W1 + b1) @ W2 + b2, g = [nc | n2q | nc*n2q | nc*q2n[b]]
// 64 rows/block, full 128 hidden cols, BK=16.
__global__ __launch_bounds__(256) void final_k(const float* __restrict__ nc,
                                               const float* __restrict__ n2q,
                                               const float* __restrict__ q2n,
                                               const float* __restrict__ W1p,
                                               const float* __restrict__ b1p,
                                               const float* __restrict__ W2p,
                                               const float* __restrict__ b2p,
                                               float* __restrict__ raw) {
    __shared__ float As[16][64 + 4];
    __shared__ float W1s[16][128];
    __shared__ float red[64][17];
    int t = threadIdx.x;
    int m0 = blockIdx.x * 64;
    int tm = t >> 4, tn = t & 15;
    int la_r = t >> 2;
    int la_k = (t & 3) * 4;
    constexpr int M = Bn * Nn;

    float acc[4][8] = {};
    for (int kt = 0; kt < 128; ++kt) {
        int k0 = kt * 16;
        {
            int row = m0 + la_r;
            int kg = k0 + la_k;
            int seg = kg >> 9;
            int d = kg & 511;
            float4 v = make_float4(0.f, 0.f, 0.f, 0.f);
            if (row < M) {
                size_t off = (size_t)row * ENC + d;
                if (seg == 0) v = *(const float4*)(nc + off);
                else if (seg == 1) v = *(const float4*)(n2q + off);
                else if (seg == 2) {
                    float4 a = *(const float4*)(nc + off);
                    float4 c = *(const float4*)(n2q + off);
                    v = make_float4(a.x * c.x, a.y * c.y, a.z * c.z, a.w * c.w);
                } else {
                    int bidx = row / Nn;
                    float4 a = *(const float4*)(nc + off);
                    float4 qv = *(const float4*)(q2n + (size_t)bidx * ENC + d);
                    v = make_float4(a.x * qv.x, a.y * qv.y, a.z * qv.z, a.w * qv.w);
                }
            }
            As[la_k + 0][la_r] = v.x; As[la_k + 1][la_r] = v.y;
            As[la_k + 2][la_r] = v.z; As[la_k + 3][la_r] = v.w;
        }
        {
#pragma unroll
            for (int r = 0; r < 2; ++r) {
                int idx = t + r * 256;
                int kr = idx >> 5;
                int nq = (idx & 31) * 4;
                *(float4*)&W1s[kr][nq] = *(const float4*)(W1p + (size_t)(k0 + kr) * 128 + nq);
            }
        }
        __syncthreads();
#pragma unroll
        for (int kk = 0; kk < 16; ++kk) {
            float4 av = *(const float4*)&As[kk][tm * 4];
            float a_[4] = {av.x, av.y, av.z, av.w};
            float4 b0 = *(const float4*)&W1s[kk][tn * 8];
            float4 b1v = *(const float4*)&W1s[kk][tn * 8 + 4];
            float b_[8] = {b0.x, b0.y, b0.z, b0.w, b1v.x, b1v.y, b1v.z, b1v.w};
#pragma unroll
            for (int i = 0; i < 4; ++i)
#pragma unroll
                for (int j = 0; j < 8; ++j) acc[i][j] = fmaf(a_[i], b_[j], acc[i][j]);
        }
        __syncthreads();
    }
    for (int i = 0; i < 4; ++i) {
        float p = 0.f;
        for (int j = 0; j < 8; ++j) {
            int h = tn * 8 + j;
            p += tanhf(acc[i][j] + b1p[h]) * W2p[h];
        }
        red[tm * 4 + i][tn] = p;
    }
    __syncthreads();
    if (t < 64) {
        int row = m0 + t;
        if (row < M) {
            float s = 0.f;
            for (int c = 0; c < 16; ++c) s += red[t][c];
            raw[row] = s + b2p[0];
        }
    }
}

// ---------------------------------------------------------------------------
// out[b,c] = max_n ( (mask? raw : 0) == 0 ? -1e6 : (mask? raw : 0) )
__global__ __launch_bounds__(256) void predmax_k(const int* __restrict__ mask,
                                                 const float* __restrict__ raw,
                                                 float* __restrict__ out) {
    int idx = blockIdx.x * 4 + (threadIdx.x >> 6);
    int lane = threadIdx.x & 63;
    if (idx >= Bn * NCn) return;
    int b = idx / NCn, c = idx - b * NCn;
    const int* mrow = mask + ((size_t)b * NCn + c) * Nn;
    const float* rrow = raw + (size_t)b * Nn;
    float mx = -INFINITY;
    for (int n = lane; n < Nn; n += 64) {
        float v = mrow[n] ? rrow[n] : 0.0f;
        if (v == 0.0f) v = -1.0e6f;
        mx = fmaxf(mx, v);
    }
    for (int off = 32; off; off >>= 1) mx = fmaxf(mx, __shfl_xor(mx, off, 64));
    if (lane == 0) out[idx] = mx;
}

}  // namespace

extern "C" void kernel_launch(void* const* d_in, const int* in_sizes, int n_in,
                              void* d_out, int out_size, void* d_ws, size_t ws_size,
                              hipStream_t stream) {
    const float* nodes_glove  = (const float*)d_in[0];
    const float* query_glove  = (const float*)d_in[1];
    const float* adj          = (const float*)d_in[2];
    const int*   nodes_length = (const int*)d_in[3];
    const int*   maskp        = (const int*)d_in[4];
    const float* Wn = (const float*)d_in[5];
    const float* bn = (const float*)d_in[6];
    const float* Wq = (const float*)d_in[7];
    const float* bq = (const float*)d_in[8];
    const float* Wh = (const float*)d_in[9];
    const float* bh = (const float*)d_in[10];
    const float* Wc = (const float*)d_in[11];
    const float* bc = (const float*)d_in[12];
    const float* wa = (const float*)d_in[13];
    const float* W1 = (const float*)d_in[14];
    const float* b1 = (const float*)d_in[15];
    const float* W2 = (const float*)d_in[16];
    const float* b2 = (const float*)d_in[17];
    float* out = (float*)d_out;

    float* ws = (float*)d_ws;
    size_t off = 0;
    auto alloc = [&](size_t n) { float* p = ws + off; off += n; return p; };
    float* nc   = alloc((size_t)Bn * Nn * ENC);
    float* lh0  = alloc((size_t)Bn * Nn * ENC);
    float* lh1  = alloc((size_t)Bn * Nn * ENC);
    float* hm   = alloc((size_t)Bn * Nn * ENC);   // reused as n2q after hops
    float* upd  = alloc((size_t)Bn * Nn * ENC);
    float* Asum = alloc((size_t)Bn * Nn * Nn);
    float* qc   = alloc((size_t)Bn * Qn * ENC);
    float* rowmax = alloc(Bn * Nn);
    float* bvec   = alloc(Bn * Nn);
    float* q2n    = alloc(Bn * ENC);
    float* raw    = alloc(Bn * Nn);
    float* n2q = hm;

    constexpr int M = Bn * Nn;  // 4000

    // adj sum over nets (once)
    {
        size_t tot = (size_t)Bn * Nn * Nn;
        sum_adj_k<<<dim3((unsigned)((tot + 255) / 256)), 256, 0, stream>>>(adj, Asum);
    }
    // nodes_compress (+ masked last_hop) and query_compress
    sgemm_k<0><<<dim3((M + 63) / 64, ENC / 64), 256, 0, stream>>>(
        nodes_glove, Wn, bn, nc, lh0, M, ENC, DIN, nodes_length);
    sgemm_k<1><<<dim3((Bn * Qn + 63) / 64, ENC / 64), 256, 0, stream>>>(
        query_glove, Wq, bq, qc, nullptr, Bn * Qn, ENC, DIN, nodes_length);

    // 3 hops
    float* cur = lh0;
    float* nxt = lh1;
    for (int h = 0; h < 3; ++h) {
        sgemm_k<2><<<dim3((M + 63) / 64, ENC / 64), 256, 0, stream>>>(
            cur, Wh, bh, hm, nullptr, M, ENC, ENC, nodes_length);
        bgemm_update_k<<<dim3((Nn + 63) / 64, ENC / 64, Bn), 256, 0, stream>>>(Asum, hm, upd);
        gemm_att_k<<<dim3((M + 63) / 64, ENC / 64), 256, 0, stream>>>(
            upd, cur, Wc, bc, nxt, nodes_length);
        float* tmp = cur; cur = nxt; nxt = tmp;
    }
    // cur == final last_hop

    sim_fused_k<<<dim3(Bn, 16), 256, 0, stream>>>(cur, qc, wa, n2q, rowmax);
    bvec_k<<<dim3(Bn), 512, 0, stream>>>(rowmax, bvec);
    q2n_k<<<dim3(Bn, ENC / 256), 256, 0, stream>>>(bvec, nc, q2n);
    final_k<<<dim3((M + 63) / 64), 256, 0, stream>>>(nc, n2q, q2n, W1, b1, W2, b2, raw);
    predmax_k<<<dim3((Bn * NCn + 3) / 4), 256, 0, stream>>>(maskp, raw, out);
}